// Round 2
// baseline (7090.391 us; speedup 1.0000x reference)
//
#include <hip/hip_runtime.h>

// ---------------------------------------------------------------------------
// ACARHead forward, fp32 baseline.
// Layout convention: all post-conv2 activations are [n][512][16][16] where the
// 14x14 payload sits at rows/cols 1..14 and the border is zero ("padded rep").
// A pad=1 3x3 conv on the 14x14 data == valid 3x3 conv on the 16x16 buffer,
// writing its (h,w) output back to padded position (h+1,w+1).
// conv2 (valid, 16x16 full data -> 14x14) is the SAME kernel.
// ---------------------------------------------------------------------------

#define XNC 131072   // 512*256 floats per sample
#define W3SZ 2359296 // 512*512*9

// ---- AdaptiveMaxPool3d(1): max over 4*7*7=196, write xp and out[:,0:1024] ----
__global__ void pool_max_kernel(const float* __restrict__ x, float* __restrict__ xp,
                                float* __restrict__ out) {
  int tid = threadIdx.x;
  int wid = blockIdx.x * 4 + (tid >> 6);   // n*1024 + c
  int lane = tid & 63;
  int n = wid >> 10, c = wid & 1023;
  const float* p = x + (size_t)wid * 196;
  float v = -3.4e38f;
  v = fmaxf(v, p[lane]);
  v = fmaxf(v, p[lane + 64]);
  v = fmaxf(v, p[lane + 128]);
  if (lane < 4) v = fmaxf(v, p[lane + 192]);
#pragma unroll
  for (int off = 32; off >= 1; off >>= 1) v = fmaxf(v, __shfl_xor(v, off));
  if (lane == 0) { xp[wid] = v; out[(size_t)n * 1536 + c] = v; }
}

// ---- bias1[n][o] = sum_{c<1024} w1[o][1024+c] * xp[n][c] ----
__global__ void bias1_kernel(const float* __restrict__ w1, const float* __restrict__ xp,
                             float* __restrict__ bias1) {
  int tid = threadIdx.x;
  int wid = blockIdx.x * 4 + (tid >> 6);   // n*512 + o
  int lane = tid & 63;
  int n = wid >> 9, o = wid & 511;
  const float* wr = w1 + (size_t)o * 2048 + 1024;
  const float* xr = xp + (size_t)n * 1024;
  float s = 0.f;
#pragma unroll
  for (int r = 0; r < 16; r++) { int c = lane + r * 64; s += wr[c] * xr[c]; }
#pragma unroll
  for (int off = 32; off >= 1; off >>= 1) s += __shfl_xor(s, off);
  if (lane == 0) bias1[wid] = s;
}

// ---- conv1: 1x1 conv, K=1024 over feat[roi[n]], + bias1, relu. Full 16x16 out.
// grid (4 p-tiles, 8 o-tiles, 32 n), 256 threads, 4o x 4p per thread.
__global__ __launch_bounds__(256) void conv1_kernel(
    const float* __restrict__ feat, const int* __restrict__ rois,
    const float* __restrict__ w1, const float* __restrict__ bias1,
    float* __restrict__ outq) {
  int n = blockIdx.z;
  int o0 = blockIdx.y * 64;
  int p0 = blockIdx.x * 64;
  int t = threadIdx.x;
  int tx = t & 15, ty = t >> 4;
  __shared__ float Xs[8][64];
  __shared__ float Ws[8][64];
  int ri = rois[n * 5];
  const float* fb = feat + (size_t)ri * 1024 * 256;
  float acc[4][4] = {};
  for (int c0 = 0; c0 < 1024; c0 += 8) {
    { // stage X: 8 rows of 64 contiguous pixels
      int r = t >> 5, col = (t & 31) * 2;
      const float* src = fb + (size_t)(c0 + r) * 256 + p0 + col;
      Xs[r][col] = src[0]; Xs[r][col + 1] = src[1];
    }
    { // stage W transposed [k][o]: 8k x 64o, 2 entries/thread (FIXED: was OOB)
      int oo = t >> 3, kk = t & 7;
      Ws[kk][oo]      = w1[(size_t)(o0 + oo) * 2048 + c0 + kk];
      Ws[kk][oo + 32] = w1[(size_t)(o0 + oo + 32) * 2048 + c0 + kk];
    }
    __syncthreads();
#pragma unroll
    for (int k = 0; k < 8; k++) {
      float4 wv = *(const float4*)&Ws[k][ty * 4];
      float4 xv = *(const float4*)&Xs[k][tx * 4];
      acc[0][0] += wv.x * xv.x; acc[0][1] += wv.x * xv.y; acc[0][2] += wv.x * xv.z; acc[0][3] += wv.x * xv.w;
      acc[1][0] += wv.y * xv.x; acc[1][1] += wv.y * xv.y; acc[1][2] += wv.y * xv.z; acc[1][3] += wv.y * xv.w;
      acc[2][0] += wv.z * xv.x; acc[2][1] += wv.z * xv.y; acc[2][2] += wv.z * xv.z; acc[2][3] += wv.z * xv.w;
      acc[3][0] += wv.w * xv.x; acc[3][1] += wv.w * xv.y; acc[3][2] += wv.w * xv.z; acc[3][3] += wv.w * xv.w;
    }
    __syncthreads();
  }
#pragma unroll
  for (int i = 0; i < 4; i++) {
    float b = bias1[(size_t)n * 512 + o0 + ty * 4 + i];
#pragma unroll
    for (int j = 0; j < 4; j++) {
      float v = acc[i][j] + b;
      outq[(size_t)n * XNC + (size_t)(o0 + ty * 4 + i) * 256 + p0 + tx * 4 + j] = fmaxf(v, 0.f);
    }
  }
}

// ---- generic valid-3x3 on a [512][16][16] buffer, write padded interior ----
// grid (4 p-tiles, 4 o-tiles of 128, 32 n), 256 threads, 8o x 4p per thread.
template <bool RELU, bool ADD>
__global__ __launch_bounds__(256) void conv3x3_kernel(
    const float* __restrict__ xin, const float* __restrict__ wt,
    float* __restrict__ out) {
  int n = blockIdx.z;
  int o0 = blockIdx.y * 128;
  int p0 = blockIdx.x * 64;
  int t = threadIdx.x;
  int tx = t & 15, ty = t >> 4;
  __shared__ float Xs[8][256];   // 8 channels, full 16x16
  __shared__ float Ws[72][128];  // k = (c-c0)*9 + tap, o-contiguous
  float acc[8][4] = {};
  const float* xn = xin + (size_t)n * XNC;
  const int pb0 = p0 + tx * 4;
  for (int c0 = 0; c0 < 512; c0 += 8) {
    { // X stage: 2048 contiguous floats
      const float4* src = (const float4*)(xn + (size_t)c0 * 256);
      float4* dst = (float4*)&Xs[0][0];
      dst[t] = src[t];
      dst[t + 256] = src[t + 256];
    }
    { // W stage transposed
      int o = t >> 1, kb = (t & 1) * 36;
      const float* src = wt + (size_t)(o0 + o) * 4608 + (size_t)c0 * 9 + kb;
#pragma unroll
      for (int k = 0; k < 36; k++) Ws[kb + k][o] = src[k];
    }
    __syncthreads();
#pragma unroll
    for (int cc = 0; cc < 8; cc++) {
#pragma unroll
      for (int t9 = 0; t9 < 9; t9++) {
        const int off = (t9 / 3) * 16 + (t9 % 3);
        const int k = cc * 9 + t9;
        float4 w0 = *(const float4*)&Ws[k][ty * 8];
        float4 w1v = *(const float4*)&Ws[k][ty * 8 + 4];
        float xv[4];
#pragma unroll
        for (int j = 0; j < 4; j++) xv[j] = Xs[cc][(pb0 + j + off) & 255];
#pragma unroll
        for (int j = 0; j < 4; j++) {
          acc[0][j] += w0.x * xv[j];
          acc[1][j] += w0.y * xv[j];
          acc[2][j] += w0.z * xv[j];
          acc[3][j] += w0.w * xv[j];
          acc[4][j] += w1v.x * xv[j];
          acc[5][j] += w1v.y * xv[j];
          acc[6][j] += w1v.z * xv[j];
          acc[7][j] += w1v.w * xv[j];
        }
      }
    }
    __syncthreads();
  }
#pragma unroll
  for (int j = 0; j < 4; j++) {
    int p = pb0 + j;
    int h = p >> 4, w = p & 15;
    if (h < 14 && w < 14) {
      int po = (h + 1) * 16 + (w + 1);
#pragma unroll
      for (int i = 0; i < 8; i++) {
        size_t oi = (size_t)n * XNC + (size_t)(o0 + ty * 8 + i) * 256 + po;
        float v = acc[i][j];
        if (RELU) v = fmaxf(v, 0.f);
        if (ADD) v += out[oi];
        out[oi] = v;
      }
    }
  }
}

// ---- att[qn][kn][pp] = (1/sqrt(512)) * sum_c q[qn][c][pp]*k[kn][c][pp] ----
__global__ __launch_bounds__(256) void att_kernel(
    const float* __restrict__ q, const float* __restrict__ k,
    float* __restrict__ att) {
  int kn = blockIdx.x, qn = blockIdx.y;
  int tid = threadIdx.x;
  if (tid >= 196) return;
  int h = tid / 14, w = tid % 14;
  int pp = (h + 1) * 16 + (w + 1);
  const float* qb = q + (size_t)qn * XNC + pp;
  const float* kb = k + (size_t)kn * XNC + pp;
  float s = 0.f;
#pragma unroll 4
  for (int c = 0; c < 512; c++) s += qb[(size_t)c * 256] * kb[(size_t)c * 256];
  att[((size_t)qn * 32 + kn) * 256 + pp] = s * 0.044194173824159216f;
}

// ---- softmax over kn ----
__global__ void softmax_kernel(float* __restrict__ att) {
  int qn = blockIdx.x, tid = threadIdx.x;
  if (tid >= 196) return;
  int h = tid / 14, w = tid % 14;
  int pp = (h + 1) * 16 + (w + 1);
  float* a = att + (size_t)qn * 32 * 256 + pp;
  float v[32];
  float m = -3.4e38f;
#pragma unroll
  for (int kn = 0; kn < 32; kn++) { v[kn] = a[kn * 256]; m = fmaxf(m, v[kn]); }
  float s = 0.f;
#pragma unroll
  for (int kn = 0; kn < 32; kn++) { v[kn] = __expf(v[kn] - m); s += v[kn]; }
  float inv = 1.f / s;
#pragma unroll
  for (int kn = 0; kn < 32; kn++) a[kn * 256] = v[kn] * inv;
}

// ---- vf[qn][c][pp] = sum_kn att[qn][kn][pp]*v[kn][c][pp]; border -> 0 ----
__global__ __launch_bounds__(256) void vf_kernel(
    const float* __restrict__ att, const float* __restrict__ v,
    float* __restrict__ outq) {
  int cg = blockIdx.x;   // 16 groups of 32 channels
  int qn = blockIdx.y;
  int pid = threadIdx.x;
  int h = pid >> 4, w = pid & 15;
  bool interior = (h >= 1 && h <= 14 && w >= 1 && w <= 14);
  float a[32];
  if (interior) {
#pragma unroll
    for (int kn = 0; kn < 32; kn++) a[kn] = att[((size_t)qn * 32 + kn) * 256 + pid];
  }
  for (int cc = 0; cc < 32; cc++) {
    int c = cg * 32 + cc;
    float s = 0.f;
    if (interior) {
#pragma unroll
      for (int kn = 0; kn < 32; kn++)
        s += a[kn] * v[(size_t)kn * XNC + (size_t)c * 256 + pid];
    }
    outq[(size_t)qn * XNC + (size_t)c * 256 + pid] = s;
  }
}

// ---- GroupNorm stats: per-n sum & sumsq over 512x196 interior ----
__global__ __launch_bounds__(256) void gn_stats_kernel(
    const float* __restrict__ vf, float* __restrict__ stats) {
  int n = blockIdx.x, tid = threadIdx.x;
  float s = 0.f, ss = 0.f;
  if (tid < 196) {
    int h = tid / 14, w = tid % 14;
    int pp = (h + 1) * 16 + (w + 1);
    const float* b = vf + (size_t)n * XNC + pp;
    for (int c = 0; c < 512; c++) { float x = b[(size_t)c * 256]; s += x; ss += x * x; }
  }
#pragma unroll
  for (int off = 32; off >= 1; off >>= 1) { s += __shfl_xor(s, off); ss += __shfl_xor(ss, off); }
  __shared__ float sm[8];
  int wv = tid >> 6, ln = tid & 63;
  if (ln == 0) { sm[wv] = s; sm[4 + wv] = ss; }
  __syncthreads();
  if (tid == 0) {
    stats[n * 2]     = sm[0] + sm[1] + sm[2] + sm[3];
    stats[n * 2 + 1] = sm[4] + sm[5] + sm[6] + sm[7];
  }
}

// ---- GroupNorm apply + affine + relu (interior only; border stays 0) ----
__global__ __launch_bounds__(256) void gn_apply_kernel(
    float* __restrict__ vf, const float* __restrict__ stats,
    const float* __restrict__ gamma, const float* __restrict__ beta) {
  int cg = blockIdx.x;  // 8 groups of 64 channels
  int n = blockIdx.y;
  int tid = threadIdx.x;
  if (tid >= 196) return;
  int h = tid / 14, w = tid % 14;
  int pp = (h + 1) * 16 + (w + 1);
  const float M = 512.f * 196.f;
  float mu = stats[n * 2] / M;
  float var = stats[n * 2 + 1] / M - mu * mu;
  float inv = rsqrtf(var + 1e-5f);
  for (int cc = 0; cc < 64; cc++) {
    int c = cg * 64 + cc;
    size_t idx = (size_t)n * XNC + (size_t)c * 256 + pp;
    float x = vf[idx];
    float y = (x - mu) * inv * gamma[c] + beta[c];
    vf[idx] = fmaxf(y, 0.f);
  }
}

// ---- final: mean over interior 196 per (n,c) -> out[n][1024+c] ----
__global__ void final_mean_kernel(const float* __restrict__ bufx, float* __restrict__ out) {
  int tid = threadIdx.x;
  int wid = blockIdx.x * 4 + (tid >> 6);  // n*512 + c
  int lane = tid & 63;
  int n = wid >> 9, c = wid & 511;
  const float* b = bufx + (size_t)n * XNC + (size_t)c * 256;
  float s = 0.f;
#pragma unroll
  for (int r = 0; r < 3; r++) {
    int idx = lane + r * 64;
    int h = idx / 14, w = idx % 14;
    s += b[(h + 1) * 16 + w + 1];
  }
  if (lane < 4) {
    int idx = 192 + lane;
    int h = idx / 14, w = idx % 14;
    s += b[(h + 1) * 16 + w + 1];
  }
#pragma unroll
  for (int off = 32; off >= 1; off >>= 1) s += __shfl_xor(s, off);
  if (lane == 0) out[(size_t)n * 1536 + 1024 + c] = s * (1.f / 196.f);
}

extern "C" void kernel_launch(void* const* d_in, const int* in_sizes, int n_in,
                              void* d_out, int out_size, void* d_ws, size_t ws_size,
                              hipStream_t stream) {
  const float* x     = (const float*)d_in[0];
  const float* feat  = (const float*)d_in[1];
  const int*   rois  = (const int*)d_in[2];
  const float* w1    = (const float*)d_in[3];
  const float* w2    = (const float*)d_in[4];
  const float* wq    = (const float*)d_in[5];
  const float* wk    = (const float*)d_in[6];
  const float* wv    = (const float*)d_in[7];
  const float* wm    = (const float*)d_in[8];
  const float* gamma = (const float*)d_in[9];
  const float* beta  = (const float*)d_in[10];
  float* out = (float*)d_out;

  float* ws    = (float*)d_ws;
  float* xp    = ws;                  // 32768
  float* bias1 = xp + 32768;          // 16384
  float* stats = bias1 + 16384;       // 64
  float* att   = stats + 64;          // 262144
  float* bufx  = att + 262144;        // 4 x 4194304
  float* bufq  = bufx + 4194304;
  float* bufk  = bufq + 4194304;
  float* bufv  = bufk + 4194304;
  const size_t total_floats = 32768 + 16384 + 64 + 262144 + 4ull * 4194304;

  // Zero workspace (padded borders must be 0; ws is poisoned 0xAA once).
  hipMemsetAsync(d_ws, 0, total_floats * sizeof(float), stream);

  pool_max_kernel<<<8192, 256, 0, stream>>>(x, xp, out);
  bias1_kernel<<<4096, 256, 0, stream>>>(w1, xp, bias1);
  conv1_kernel<<<dim3(4, 8, 32), 256, 0, stream>>>(feat, rois, w1, bias1, bufq);
  // conv2: valid 3x3 on full 16x16 data -> padded rep, relu
  conv3x3_kernel<true, false><<<dim3(4, 4, 32), 256, 0, stream>>>(bufq, w2, bufx);

  for (int i = 0; i < 3; i++) {
    const float* wqi = wq + (size_t)i * W3SZ;
    const float* wki = wk + (size_t)i * W3SZ;
    const float* wvi = wv + (size_t)i * W3SZ;
    const float* wmi = wm + (size_t)i * W3SZ;
    conv3x3_kernel<false, false><<<dim3(4, 4, 32), 256, 0, stream>>>(bufx, wqi, bufq);
    conv3x3_kernel<false, false><<<dim3(4, 4, 32), 256, 0, stream>>>(bufx, wki, bufk);
    conv3x3_kernel<false, false><<<dim3(4, 4, 32), 256, 0, stream>>>(bufx, wvi, bufv);
    att_kernel<<<dim3(32, 32), 256, 0, stream>>>(bufq, bufk, att);
    softmax_kernel<<<32, 256, 0, stream>>>(att);
    vf_kernel<<<dim3(16, 32), 256, 0, stream>>>(att, bufv, bufq);
    gn_stats_kernel<<<32, 256, 0, stream>>>(bufq, stats);
    gn_apply_kernel<<<dim3(8, 32), 256, 0, stream>>>(bufq, stats, gamma + i * 512, beta + i * 512);
    // wm conv + residual add into bufx
    conv3x3_kernel<false, true><<<dim3(4, 4, 32), 256, 0, stream>>>(bufq, wmi, bufx);
  }

  final_mean_kernel<<<4096, 256, 0, stream>>>(bufx, out);
}

// Round 3
// 1259.588 us; speedup vs baseline: 5.6291x; 5.6291x over previous
//
#include <hip/hip_runtime.h>

// ---------------------------------------------------------------------------
// ACARHead forward, bf16-MFMA convs.
// Activation layout: bf16 [n][p=256][c] (c contiguous). p is the padded 16x16
// coordinate; 14x14 payload at rows/cols 1..14, border rows ZERO.
// A pad=1 3x3 conv == valid 3x3 on the 16x16 buffer (tap offset = dh*16+dw,
// &255 row wrap inside LDS; wrapped rows only feed discarded outputs).
// Weights pre-converted once per launch: Wg[o][tap][c] bf16.
// ---------------------------------------------------------------------------

typedef __attribute__((ext_vector_type(8))) short bhalf8;
typedef __attribute__((ext_vector_type(4))) float floatx4;

#define ACT_N 131072   // 256*512 bf16 elements per sample
#define W3SZ  2359296  // 512*512*9

__device__ inline float b2f(unsigned short u) {
  union { unsigned int i; float f; } x; x.i = ((unsigned int)u) << 16; return x.f;
}
__device__ inline unsigned short f2b(float f) {
  union { float f; unsigned int i; } x; x.f = f;
  return (unsigned short)((x.i + 0x7FFFu + ((x.i >> 16) & 1u)) >> 16);
}

// ---- AdaptiveMaxPool3d(1): max over 196, write xp (f32) and out[:,0:1024] ----
__global__ void pool_max_kernel(const float* __restrict__ x, float* __restrict__ xp,
                                float* __restrict__ out) {
  int tid = threadIdx.x;
  int wid = blockIdx.x * 4 + (tid >> 6);   // n*1024 + c
  int lane = tid & 63;
  int n = wid >> 10, c = wid & 1023;
  const float* p = x + (size_t)wid * 196;
  float v = -3.4e38f;
  v = fmaxf(v, p[lane]);
  v = fmaxf(v, p[lane + 64]);
  v = fmaxf(v, p[lane + 128]);
  if (lane < 4) v = fmaxf(v, p[lane + 192]);
#pragma unroll
  for (int off = 32; off >= 1; off >>= 1) v = fmaxf(v, __shfl_xor(v, off));
  if (lane == 0) { xp[wid] = v; out[(size_t)n * 1536 + c] = v; }
}

// ---- bias1[n][o] = sum_{c<1024} w1[o][1024+c] * xp[n][c]  (f32) ----
__global__ void bias1_kernel(const float* __restrict__ w1, const float* __restrict__ xp,
                             float* __restrict__ bias1) {
  int tid = threadIdx.x;
  int wid = blockIdx.x * 4 + (tid >> 6);   // n*512 + o
  int lane = tid & 63;
  int n = wid >> 9, o = wid & 511;
  const float* wr = w1 + (size_t)o * 2048 + 1024;
  const float* xr = xp + (size_t)n * 1024;
  float s = 0.f;
#pragma unroll
  for (int r = 0; r < 16; r++) { int c = lane + r * 64; s += wr[c] * xr[c]; }
#pragma unroll
  for (int off = 32; off >= 1; off >>= 1) s += __shfl_xor(s, off);
  if (lane == 0) bias1[wid] = s;
}

// ---- 3x3 weight prep: w[o][c][t9] f32 -> Wg[tid][o][t9][c] bf16 ----
// tensor order: 0=w2, 1+4d=wq[d], 2+4d=wk[d], 3+4d=wv[d], 4+4d=wm[d]
__global__ __launch_bounds__(256) void wprep_kernel(
    const float* __restrict__ w2, const float* __restrict__ wq,
    const float* __restrict__ wk, const float* __restrict__ wv,
    const float* __restrict__ wm, unsigned short* __restrict__ Wg) {
  int o = blockIdx.x, tid = blockIdx.y, t = threadIdx.x;
  const float* src;
  if (tid == 0) src = w2;
  else {
    int d = (tid - 1) >> 2, r = (tid - 1) & 3;
    src = (r == 0 ? wq : r == 1 ? wk : r == 2 ? wv : wm) + (size_t)d * W3SZ;
  }
  src += (size_t)o * 4608;
  __shared__ float S[4608];
#pragma unroll
  for (int i = 0; i < 18; i++) S[t + i * 256] = src[t + i * 256];
  __syncthreads();
  unsigned short* dst = Wg + ((size_t)tid * 512 + o) * 4608;
#pragma unroll
  for (int i = 0; i < 18; i++) {
    int idx = t + i * 256;
    int t9 = idx >> 9, c = idx & 511;
    dst[idx] = f2b(S[c * 9 + t9]);
  }
}

// ---- conv1 weight prep: w1[o][c<1024] f32 -> W1g[o][c] bf16 ----
__global__ void w1prep_kernel(const float* __restrict__ w1, unsigned short* __restrict__ W1g) {
  int idx = blockIdx.x * 256 + threadIdx.x;  // < 524288
  int o = idx >> 10, c = idx & 1023;
  W1g[idx] = f2b(w1[(size_t)o * 2048 + c]);
}

// ---- feat transpose: feat[img][c][p] f32 -> featT[img][p][c] bf16 ----
__global__ __launch_bounds__(256) void ftprep_kernel(
    const float* __restrict__ feat, unsigned short* __restrict__ featT) {
  int img = blockIdx.z, c0 = blockIdx.y * 64, p0 = blockIdx.x * 64;
  int t = threadIdx.x;
  int a = t >> 6, b = t & 63;
  __shared__ float S[64][65];
#pragma unroll
  for (int j = 0; j < 16; j++) {
    int r = a * 16 + j;
    S[r][b] = feat[((size_t)img * 1024 + c0 + r) * 256 + p0 + b];
  }
  __syncthreads();
#pragma unroll
  for (int j = 0; j < 16; j++) {
    int pl = a * 16 + j;
    featT[((size_t)img * 256 + p0 + pl) * 1024 + c0 + b] = f2b(S[b][pl]);
  }
}

// ---------------------------------------------------------------------------
// Unified MFMA conv. o-tile = 64. K staged in 32-channel blocks.
// LDS fragment-order layouts (16B units, bank-even):
//   Xs[kgrp(4)][p(256)] ; Ws[(t9*4+kg)(TAPS*4)][o(64)] with o^((t9*4+kg)&7)
// Wave tile: 64o x (NREP*16)p  (M_rep=4, N_rep=NREP fragments of 16x16x32).
// ---------------------------------------------------------------------------
template <int TAPS, int KTOT, int WAVES, int NREP, int PSPLIT,
          bool RELU, bool ADD, bool BIAS, bool VALID>
__global__ __launch_bounds__(WAVES * 64) void conv_mfma_kernel(
    const unsigned short* __restrict__ Xg, const int* __restrict__ rois,
    const unsigned short* __restrict__ Wg, const float* __restrict__ bias,
    unsigned short* __restrict__ Out) {
  constexpr int THREADS = WAVES * 64;
  static_assert(PSPLIT * WAVES * NREP * 16 == 256, "p coverage");
  int n = blockIdx.y;
  int o0 = (blockIdx.x / PSPLIT) * 64;
  int pq = blockIdx.x % PSPLIT;
  int t = threadIdx.x;
  int wv = t >> 6, l = t & 63, l15 = l & 15, l4 = l >> 4;
  int pbase = (pq * WAVES + wv) * (NREP * 16);
  const unsigned short* xb =
      Xg + (rois ? (size_t)rois[n * 5] * 256 * KTOT : (size_t)n * 256 * KTOT);
  __shared__ bhalf8 Xs[1024];
  __shared__ bhalf8 Ws[TAPS * 256];
  floatx4 acc[4][NREP] = {};

  for (int c0 = 0; c0 < KTOT; c0 += 32) {
#pragma unroll
    for (int i = 0; i < 1024 / THREADS; i++) {
      int u = t + i * THREADS;
      int kg = u & 3, p = u >> 2;
      Xs[kg * 256 + p] = *(const bhalf8*)(xb + (size_t)p * KTOT + c0 + kg * 8);
    }
#pragma unroll
    for (int i = 0; i < (TAPS * 256) / THREADS; i++) {
      int u = t + i * THREADS;
      int r = u % (TAPS * 4);
      int o = u / (TAPS * 4);
      int t9 = r >> 2, kg = r & 3;
      Ws[r * 64 + (o ^ (r & 7))] =
          *(const bhalf8*)(Wg + ((size_t)(o0 + o) * TAPS + t9) * KTOT + c0 + kg * 8);
    }
    __syncthreads();
#pragma unroll
    for (int t9 = 0; t9 < TAPS; t9++) {
      const int off = VALID ? (t9 / 3) * 16 + (t9 % 3) : 0;
      bhalf8 b[NREP];
#pragma unroll
      for (int pf = 0; pf < NREP; pf++) {
        int row = (pbase + pf * 16 + l15 + off) & 255;
        b[pf] = Xs[l4 * 256 + row];
      }
#pragma unroll
      for (int of = 0; of < 4; of++) {
        int rr = t9 * 4 + l4;
        bhalf8 a = Ws[rr * 64 + ((of * 16 + l15) ^ (rr & 7))];
#pragma unroll
        for (int pf = 0; pf < NREP; pf++)
          acc[of][pf] = __builtin_amdgcn_mfma_f32_16x16x32_bf16(a, b[pf], acc[of][pf], 0, 0, 0);
      }
    }
    __syncthreads();
  }

#pragma unroll
  for (int of = 0; of < 4; of++) {
    int og = o0 + of * 16 + l4 * 4;
    int tensor = og >> 9, ol = og & 511;
#pragma unroll
    for (int pf = 0; pf < NREP; pf++) {
      int p = pbase + pf * 16 + l15;
      int po = p;
      if (VALID) {
        int h = p >> 4, w = p & 15;
        if (h >= 14 || w >= 14) continue;
        po = (h + 1) * 16 + (w + 1);
      }
      unsigned short* dp = Out + (((size_t)tensor * 32 + n) * 256 + po) * 512 + ol;
      float vv[4];
#pragma unroll
      for (int r2 = 0; r2 < 4; r2++) vv[r2] = acc[of][pf][r2];
      if (BIAS) {
#pragma unroll
        for (int r2 = 0; r2 < 4; r2++) vv[r2] += bias[(size_t)n * 512 + ol + r2];
      }
      if (ADD) {
        ushort4 old = *(const ushort4*)dp;
        vv[0] += b2f(old.x); vv[1] += b2f(old.y); vv[2] += b2f(old.z); vv[3] += b2f(old.w);
      }
      if (RELU) {
#pragma unroll
        for (int r2 = 0; r2 < 4; r2++) vv[r2] = fmaxf(vv[r2], 0.f);
      }
      ushort4 st = { f2b(vv[0]), f2b(vv[1]), f2b(vv[2]), f2b(vv[3]) };
      *(ushort4*)dp = st;
    }
  }
}

// ---- att[qn][pp][kn] = (1/sqrt(512)) * sum_c q[qn][pp][c]*k[kn][pp][c] ----
__global__ __launch_bounds__(256) void att2_kernel(
    const unsigned short* __restrict__ q, const unsigned short* __restrict__ k,
    float* __restrict__ att) {
  int kn = blockIdx.x, qn = blockIdx.y;
  int t = threadIdx.x, wv = t >> 6, l = t & 63;
  const unsigned short* qb = q + (size_t)qn * ACT_N;
  const unsigned short* kb = k + (size_t)kn * ACT_N;
  for (int i = wv; i < 196; i += 4) {
    int pp = (i / 14 + 1) * 16 + (i % 14) + 1;
    bhalf8 qv = *(const bhalf8*)(qb + pp * 512 + l * 8);
    bhalf8 kv = *(const bhalf8*)(kb + pp * 512 + l * 8);
    float s = 0.f;
#pragma unroll
    for (int j = 0; j < 8; j++)
      s += b2f((unsigned short)qv[j]) * b2f((unsigned short)kv[j]);
#pragma unroll
    for (int off = 32; off >= 1; off >>= 1) s += __shfl_xor(s, off);
    if (l == 0) att[((size_t)qn * 256 + pp) * 32 + kn] = s * 0.044194173824159216f;
  }
}

// ---- softmax over kn (32 contiguous f32 per (qn,pp)) ----
__global__ void softmax2_kernel(float* __restrict__ att) {
  int qn = blockIdx.x, t = threadIdx.x;
  if (t >= 196) return;
  int pp = (t / 14 + 1) * 16 + (t % 14) + 1;
  float* a = att + ((size_t)qn * 256 + pp) * 32;
  float v[32]; float m = -3.4e38f;
#pragma unroll
  for (int i = 0; i < 32; i++) { v[i] = a[i]; m = fmaxf(m, v[i]); }
  float s = 0.f;
#pragma unroll
  for (int i = 0; i < 32; i++) { v[i] = __expf(v[i] - m); s += v[i]; }
  float inv = 1.f / s;
#pragma unroll
  for (int i = 0; i < 32; i++) a[i] = v[i] * inv;
}

// ---- vf[qn][p][c] = sum_kn att[qn][p][kn]*v[kn][p][c]; border rows -> 0 ----
__global__ __launch_bounds__(256) void vf2_kernel(
    const float* __restrict__ att, const unsigned short* __restrict__ v,
    unsigned short* __restrict__ o) {
  int p = blockIdx.x, t = threadIdx.x;
  int h = p >> 4, w = p & 15;
  if (h < 1 || h > 14 || w < 1 || w > 14) {
    for (int qn = 0; qn < 32; qn++)
      *(unsigned int*)(o + ((size_t)qn * 256 + p) * 512 + t * 2) = 0u;
    return;
  }
  __shared__ float attS[1024];
  __shared__ unsigned short vS[32 * 512];
#pragma unroll
  for (int i = 0; i < 4; i++) {
    int idx = t + i * 256;
    int qn = idx >> 5, kn = idx & 31;
    attS[idx] = att[((size_t)qn * 256 + p) * 32 + kn];
  }
#pragma unroll
  for (int i = 0; i < 8; i++) {
    int u = t + i * 256;
    int kn = u >> 6, cu = (u & 63) * 8;
    *(bhalf8*)&vS[kn * 512 + cu] = *(const bhalf8*)(v + ((size_t)kn * 256 + p) * 512 + cu);
  }
  __syncthreads();
  int c2 = t * 2;
  for (int qn = 0; qn < 32; qn++) {
    float s0 = 0.f, s1 = 0.f;
#pragma unroll
    for (int kn = 0; kn < 32; kn++) {
      float a = attS[qn * 32 + kn];
      unsigned int vv = *(const unsigned int*)&vS[kn * 512 + c2];
      s0 += a * b2f((unsigned short)vv);
      s1 += a * b2f((unsigned short)(vv >> 16));
    }
    unsigned int pkd = (unsigned int)f2b(s0) | ((unsigned int)f2b(s1) << 16);
    *(unsigned int*)(o + ((size_t)qn * 256 + p) * 512 + c2) = pkd;
  }
}

// ---- GroupNorm stats over interior (196 x 512) per n ----
__global__ __launch_bounds__(256) void gnstats2_kernel(
    const unsigned short* __restrict__ x, float* __restrict__ stats) {
  int n = blockIdx.x, t = threadIdx.x;
  const unsigned short* xb = x + (size_t)n * ACT_N;
  float s = 0.f, ss = 0.f;
  for (int i = 0; i < 196; i++) {
    int pp = (i / 14 + 1) * 16 + (i % 14) + 1;
    unsigned int vv = *(const unsigned int*)(xb + pp * 512 + t * 2);
    float a = b2f((unsigned short)vv), b = b2f((unsigned short)(vv >> 16));
    s += a + b; ss += a * a + b * b;
  }
#pragma unroll
  for (int off = 32; off >= 1; off >>= 1) { s += __shfl_xor(s, off); ss += __shfl_xor(ss, off); }
  __shared__ float sm[8];
  int wv = t >> 6, ln = t & 63;
  if (ln == 0) { sm[wv] = s; sm[4 + wv] = ss; }
  __syncthreads();
  if (t == 0) {
    stats[n * 2]     = sm[0] + sm[1] + sm[2] + sm[3];
    stats[n * 2 + 1] = sm[4] + sm[5] + sm[6] + sm[7];
  }
}

// ---- GroupNorm apply + affine + relu (interior only) ----
__global__ __launch_bounds__(256) void gnapply2_kernel(
    unsigned short* __restrict__ x, const float* __restrict__ stats,
    const float* __restrict__ gamma, const float* __restrict__ beta) {
  int n = blockIdx.y, t = threadIdx.x;
  int c2 = t * 2;
  unsigned short* xb = x + (size_t)n * ACT_N;
  const float M = 512.f * 196.f;
  float mu = stats[n * 2] / M;
  float var = stats[n * 2 + 1] / M - mu * mu;
  float inv = rsqrtf(var + 1e-5f);
  float g0 = gamma[c2], g1 = gamma[c2 + 1];
  float be0 = beta[c2], be1 = beta[c2 + 1];
  for (int j = 0; j < 28; j++) {
    int i = blockIdx.x * 28 + j;
    int pp = (i / 14 + 1) * 16 + (i % 14) + 1;
    unsigned int vv = *(unsigned int*)(xb + pp * 512 + c2);
    float a = (b2f((unsigned short)vv) - mu) * inv * g0 + be0;
    float b = (b2f((unsigned short)(vv >> 16)) - mu) * inv * g1 + be1;
    a = fmaxf(a, 0.f); b = fmaxf(b, 0.f);
    *(unsigned int*)(xb + pp * 512 + c2) =
        (unsigned int)f2b(a) | ((unsigned int)f2b(b) << 16);
  }
}

// ---- final: mean over interior 196 -> out[n][1024+c] (f32) ----
__global__ void fmean2_kernel(const unsigned short* __restrict__ x, float* __restrict__ out) {
  int n = blockIdx.x, t = threadIdx.x;
  const unsigned short* xb = x + (size_t)n * ACT_N;
  float s0 = 0.f, s1 = 0.f;
  for (int i = 0; i < 196; i++) {
    int pp = (i / 14 + 1) * 16 + (i % 14) + 1;
    unsigned int vv = *(const unsigned int*)(xb + pp * 512 + t * 2);
    s0 += b2f((unsigned short)vv);
    s1 += b2f((unsigned short)(vv >> 16));
  }
  out[(size_t)n * 1536 + 1024 + t * 2]     = s0 * (1.f / 196.f);
  out[(size_t)n * 1536 + 1024 + t * 2 + 1] = s1 * (1.f / 196.f);
}

extern "C" void kernel_launch(void* const* d_in, const int* in_sizes, int n_in,
                              void* d_out, int out_size, void* d_ws, size_t ws_size,
                              hipStream_t stream) {
  const float* x     = (const float*)d_in[0];
  const float* feat  = (const float*)d_in[1];
  const int*   rois  = (const int*)d_in[2];
  const float* w1    = (const float*)d_in[3];
  const float* w2    = (const float*)d_in[4];
  const float* wq    = (const float*)d_in[5];
  const float* wk    = (const float*)d_in[6];
  const float* wv    = (const float*)d_in[7];
  const float* wm    = (const float*)d_in[8];
  const float* gamma = (const float*)d_in[9];
  const float* beta  = (const float*)d_in[10];
  float* out = (float*)d_out;

  // ---- workspace layout ----
  float* wsf   = (float*)d_ws;
  float* xp    = wsf;                // 32768
  float* bias1 = xp + 32768;         // 16384
  float* stats = bias1 + 16384;      // 64
  float* att   = stats + 64;         // 262144  ([qn][pp][kn] f32)
  unsigned short* ub    = (unsigned short*)(att + 262144);
  unsigned short* featT = ub;                    // 8*256*1024   = 2097152
  unsigned short* W1g   = featT + 2097152;       // 512*1024     = 524288
  unsigned short* Wg    = W1g + 524288;          // 13*512*4608  = 30670848
  unsigned short* bufq  = Wg + 30670848;         // 4194304 each, q/k/v contiguous
  unsigned short* bufk  = bufq + 4194304;
  unsigned short* bufv  = bufk + 4194304;
  unsigned short* bufx  = bufv + 4194304;

  // bufx border rows must be zero (only interior ever written by convs)
  hipMemsetAsync(bufx, 0, (size_t)4194304 * 2, stream);

  pool_max_kernel<<<8192, 256, 0, stream>>>(x, xp, out);
  bias1_kernel<<<4096, 256, 0, stream>>>(w1, xp, bias1);
  wprep_kernel<<<dim3(512, 13), 256, 0, stream>>>(w2, wq, wk, wv, wm, Wg);
  w1prep_kernel<<<2048, 256, 0, stream>>>(w1, W1g);
  ftprep_kernel<<<dim3(4, 16, 8), 256, 0, stream>>>(feat, featT);

  // conv1: 1x1, K=1024, +bias1, relu, full 16x16 output -> bufq (as scratch A1)
  conv_mfma_kernel<1, 1024, 4, 4, 1, true, false, true, false>
      <<<dim3(8, 32), 256, 0, stream>>>(featT, rois, W1g, bias1, bufq);
  // conv2: valid 3x3 on A1 -> padded interior of bufx, relu
  conv_mfma_kernel<9, 512, 2, 4, 2, true, false, false, true>
      <<<dim3(16, 32), 128, 0, stream>>>(bufq, nullptr, Wg, nullptr, bufx);

  for (int d = 0; d < 3; d++) {
    // q,k,v batched: O=1536 over contiguous weight tensors and output buffers
    conv_mfma_kernel<9, 512, 2, 8, 1, false, false, false, true>
        <<<dim3(24, 32), 128, 0, stream>>>(bufx, nullptr,
            Wg + (size_t)(1 + 4 * d) * W3SZ, nullptr, bufq);
    att2_kernel<<<dim3(32, 32), 256, 0, stream>>>(bufq, bufk, att);
    softmax2_kernel<<<32, 256, 0, stream>>>(att);
    vf2_kernel<<<256, 256, 0, stream>>>(att, bufv, bufq);
    gnstats2_kernel<<<32, 256, 0, stream>>>(bufq, stats);
    gnapply2_kernel<<<dim3(7, 32), 256, 0, stream>>>(bufq, stats,
        gamma + d * 512, beta + d * 512);
    // wm conv + residual add into bufx
    conv_mfma_kernel<9, 512, 2, 4, 2, false, true, false, true>
        <<<dim3(16, 32), 128, 0, stream>>>(bufq, nullptr,
            Wg + (size_t)(4 + 4 * d) * W3SZ, nullptr, bufx);
  }

  fmean2_kernel<<<32, 256, 0, stream>>>(bufx, out);
}

// Round 4
// 1063.023 us; speedup vs baseline: 6.6700x; 1.1849x over previous
//
#include <hip/hip_runtime.h>

// ---------------------------------------------------------------------------
// ACARHead forward, bf16-MFMA convs with tap-shared B-fragments and
// global_load_lds staging from a pre-blocked weight layout.
// Activation layout: bf16 [n][p=256][c] (c contiguous); 14x14 payload at
// rows/cols 1..14 of the 16x16 p-grid, border zero.
// ---------------------------------------------------------------------------

typedef __attribute__((ext_vector_type(8))) short bhalf8;
typedef __attribute__((ext_vector_type(4))) float floatx4;

#define ACT_N 131072   // 256*512 bf16 elements per sample
#define W3SZ  2359296  // 512*512*9 (also = blocked per-tensor short count)

__device__ inline float b2f(unsigned short u) {
  union { unsigned int i; float f; } x; x.i = ((unsigned int)u) << 16; return x.f;
}
__device__ inline unsigned short f2b(float f) {
  union { float f; unsigned int i; } x; x.f = f;
  return (unsigned short)((x.i + 0x7FFFu + ((x.i >> 16) & 1u)) >> 16);
}
__device__ inline void gload_lds16(const unsigned short* g, bhalf8* l) {
  __builtin_amdgcn_global_load_lds(
      (const __attribute__((address_space(1))) unsigned int*)(const void*)g,
      (__attribute__((address_space(3))) unsigned int*)(void*)l, 16, 0, 0);
}

// ---- AdaptiveMaxPool3d(1): max over 196, write xp (f32) and out[:,0:1024] ----
__global__ void pool_max_kernel(const float* __restrict__ x, float* __restrict__ xp,
                                float* __restrict__ out) {
  int tid = threadIdx.x;
  int wid = blockIdx.x * 4 + (tid >> 6);   // n*1024 + c
  int lane = tid & 63;
  int n = wid >> 10, c = wid & 1023;
  const float* p = x + (size_t)wid * 196;
  float v = -3.4e38f;
  v = fmaxf(v, p[lane]);
  v = fmaxf(v, p[lane + 64]);
  v = fmaxf(v, p[lane + 128]);
  if (lane < 4) v = fmaxf(v, p[lane + 192]);
#pragma unroll
  for (int off = 32; off >= 1; off >>= 1) v = fmaxf(v, __shfl_xor(v, off));
  if (lane == 0) { xp[wid] = v; out[(size_t)n * 1536 + c] = v; }
}

// ---- bias1[n][o] = sum_{c<1024} w1[o][1024+c] * xp[n][c]  (f32) ----
__global__ void bias1_kernel(const float* __restrict__ w1, const float* __restrict__ xp,
                             float* __restrict__ bias1) {
  int tid = threadIdx.x;
  int wid = blockIdx.x * 4 + (tid >> 6);   // n*512 + o
  int lane = tid & 63;
  int n = wid >> 9, o = wid & 511;
  const float* wr = w1 + (size_t)o * 2048 + 1024;
  const float* xr = xp + (size_t)n * 1024;
  float s = 0.f;
#pragma unroll
  for (int r = 0; r < 16; r++) { int c = lane + r * 64; s += wr[c] * xr[c]; }
#pragma unroll
  for (int off = 32; off >= 1; off >>= 1) s += __shfl_xor(s, off);
  if (lane == 0) bias1[wid] = s;
}

// ---- 3x3 weight prep -> blocked LDS-slot-linear layout ----
// Wg2[tensor][ot(8)][ks(16)][slot u(2304)][8 bf16], slot u: r=u>>6, o=u&63,
// t9=r>>2, kg=r&3; data = w[o0+o][c0+kg*8+j][t9].
// grid (16 ks, 8 ot, 13 tensor), 256 threads.
__global__ __launch_bounds__(256) void wprep3_kernel(
    const float* __restrict__ w2, const float* __restrict__ wq,
    const float* __restrict__ wk, const float* __restrict__ wv,
    const float* __restrict__ wm, unsigned short* __restrict__ Wg2) {
  int ks = blockIdx.x, ot = blockIdx.y, tid = blockIdx.z;
  int t = threadIdx.x;
  const float* src;
  if (tid == 0) src = w2;
  else {
    int d = (tid - 1) >> 2, r = (tid - 1) & 3;
    src = (r == 0 ? wq : r == 1 ? wk : r == 2 ? wv : wm) + (size_t)d * W3SZ;
  }
  // submatrix rows o0..o0+64, cols [ks*288, ks*288+288) of the 4608-wide row
  __shared__ unsigned short S[64 * 288];
  const float* sb = src + (size_t)ot * 64 * 4608 + (size_t)ks * 288;
  for (int j = 0; j < 72; j++) {
    int flat = j * 256 + t;          // < 18432
    int o = flat / 288, ci = flat % 288;
    S[flat] = f2b(sb[(size_t)o * 4608 + ci]);
  }
  __syncthreads();
  unsigned short* dst = Wg2 + (((size_t)(tid * 8 + ot) * 16 + ks) * 2304) * 8;
#pragma unroll
  for (int s = 0; s < 9; s++) {
    int u = t + s * 256;
    int r = u >> 6, o = u & 63;
    int t9 = r >> 2, kg = r & 3;
    bhalf8 v;
#pragma unroll
    for (int j = 0; j < 8; j++) v[j] = (short)S[o * 288 + (kg * 8 + j) * 9 + t9];
    *(bhalf8*)(dst + (size_t)u * 8) = v;
  }
}

// ---- conv1 weight prep -> blocked: W1g[ot(8)][ks(32)][slot(256)][8] ----
// slot u: kg=u>>6, o=u&63; data = w1[o0+o][ks*32+kg*8+j]
__global__ void w1prep_kernel(const float* __restrict__ w1, unsigned short* __restrict__ W1g) {
  int ks = blockIdx.x, ot = blockIdx.y, t = threadIdx.x;
  int kg = t >> 6, o = t & 63;
  const float* s = w1 + (size_t)(ot * 64 + o) * 2048 + ks * 32 + kg * 8;
  bhalf8 v;
#pragma unroll
  for (int j = 0; j < 8; j++) v[j] = (short)f2b(s[j]);
  *(bhalf8*)(W1g + (((size_t)ot * 32 + ks) * 256 + t) * 8) = v;
}

// ---- feat transpose: feat[img][c][p] f32 -> featT[img][p][c] bf16 ----
__global__ __launch_bounds__(256) void ftprep_kernel(
    const float* __restrict__ feat, unsigned short* __restrict__ featT) {
  int img = blockIdx.z, c0 = blockIdx.y * 64, p0 = blockIdx.x * 64;
  int t = threadIdx.x;
  int a = t >> 6, b = t & 63;
  __shared__ float S[64][65];
#pragma unroll
  for (int j = 0; j < 16; j++) {
    int r = a * 16 + j;
    S[r][b] = feat[((size_t)img * 1024 + c0 + r) * 256 + p0 + b];
  }
  __syncthreads();
#pragma unroll
  for (int j = 0; j < 16; j++) {
    int pl = a * 16 + j;
    featT[((size_t)img * 256 + p0 + pl) * 1024 + c0 + b] = f2b(S[b][pl]);
  }
}

// ---------------------------------------------------------------------------
// Unified MFMA conv. o-tile = 64, K staged in 32-channel steps.
// LDS: Xs slot u = kg*256 + p (16B frags); Ws slot u = (t9*4+kg)*64 + o.
// Both staged via global_load_lds (LDS-linear, 16B/lane).
// Wave tile: 64o x (NREP*16)p. TAPS==9 uses tap-shifted B-frag sharing:
//   B(pf,dh,dw) = window[pf+dh][dw]  (fragments are 16-p-aligned).
// ---------------------------------------------------------------------------
template <int TAPS, int KTOT, int WAVES, int NREP, int PSPLIT,
          bool RELU, bool ADD, bool BIAS, bool VALID>
__global__ __launch_bounds__(WAVES * 64) void conv_mfma_kernel(
    const unsigned short* __restrict__ Xg, const int* __restrict__ rois,
    const unsigned short* __restrict__ Wg, const float* __restrict__ bias,
    unsigned short* __restrict__ Out) {
  constexpr int THREADS = WAVES * 64;
  constexpr int WSLOTS = TAPS * 4 * 64;
  constexpr int NK = KTOT / 32;
  static_assert(PSPLIT * WAVES * NREP * 16 == 256, "p coverage");
  int n = blockIdx.y;
  int ot = blockIdx.x / PSPLIT;
  int pq = blockIdx.x % PSPLIT;
  int t = threadIdx.x;
  int wv = t >> 6, l = t & 63, l15 = l & 15, l4 = l >> 4;
  int pbase = (pq * WAVES + wv) * (NREP * 16);
  const unsigned short* xb =
      Xg + (rois ? (size_t)rois[n * 5] * 256 * KTOT : (size_t)n * 256 * KTOT);
  __shared__ bhalf8 Xs[1024];
  __shared__ bhalf8 Ws[WSLOTS];
  floatx4 acc[4][NREP] = {};

  for (int ks = 0; ks < NK; ks++) {
    const int c0 = ks * 32;
    // ---- stage X: slot u = kg*256+p; global = xb + p*KTOT + c0 + kg*8 ----
#pragma unroll
    for (int i = 0; i < 1024 / THREADS; i++) {
      int base = i * THREADS + wv * 64;
      int u = base + l;
      int p = u & 255, kg = u >> 8;
      gload_lds16(xb + (size_t)p * KTOT + c0 + kg * 8, &Xs[base]);
    }
    // ---- stage W: LDS-linear from blocked global ----
    const unsigned short* wb = Wg + ((size_t)ot * NK + ks) * (WSLOTS * 8);
#pragma unroll
    for (int i = 0; i < WSLOTS / THREADS; i++) {
      int base = i * THREADS + wv * 64;
      gload_lds16(wb + (size_t)(base + l) * 8, &Ws[base]);
    }
    __syncthreads();

    if constexpr (TAPS == 9) {
#pragma unroll
      for (int dw = 0; dw < 3; dw++) {
        bhalf8 BW[NREP + 2];
#pragma unroll
        for (int w10 = 0; w10 < NREP + 2; w10++) {
          int row = (pbase + w10 * 16 + l15 + dw) & 255;
          BW[w10] = Xs[l4 * 256 + row];
        }
#pragma unroll
        for (int dh = 0; dh < 3; dh++) {
          const int rr = (dh * 3 + dw) * 4 + l4;
          bhalf8 A[4];
#pragma unroll
          for (int of = 0; of < 4; of++) A[of] = Ws[rr * 64 + of * 16 + l15];
#pragma unroll
          for (int of = 0; of < 4; of++)
#pragma unroll
            for (int pf = 0; pf < NREP; pf++)
              acc[of][pf] = __builtin_amdgcn_mfma_f32_16x16x32_bf16(
                  A[of], BW[pf + dh], acc[of][pf], 0, 0, 0);
        }
      }
    } else {
      bhalf8 B[NREP];
#pragma unroll
      for (int pf = 0; pf < NREP; pf++) {
        int row = (pbase + pf * 16 + l15) & 255;
        B[pf] = Xs[l4 * 256 + row];
      }
#pragma unroll
      for (int of = 0; of < 4; of++) {
        bhalf8 A = Ws[l4 * 64 + of * 16 + l15];
#pragma unroll
        for (int pf = 0; pf < NREP; pf++)
          acc[of][pf] = __builtin_amdgcn_mfma_f32_16x16x32_bf16(
              A, B[pf], acc[of][pf], 0, 0, 0);
      }
    }
    __syncthreads();
  }

#pragma unroll
  for (int of = 0; of < 4; of++) {
    int og = ot * 64 + of * 16 + l4 * 4;
    int tensor = og >> 9, ol = og & 511;
#pragma unroll
    for (int pf = 0; pf < NREP; pf++) {
      int p = pbase + pf * 16 + l15;
      int po = p;
      if (VALID) {
        int h = p >> 4, w = p & 15;
        if (h >= 14 || w >= 14) continue;
        po = (h + 1) * 16 + (w + 1);
      }
      unsigned short* dp = Out + (((size_t)tensor * 32 + n) * 256 + po) * 512 + ol;
      float vv[4];
#pragma unroll
      for (int r2 = 0; r2 < 4; r2++) vv[r2] = acc[of][pf][r2];
      if (BIAS) {
#pragma unroll
        for (int r2 = 0; r2 < 4; r2++) vv[r2] += bias[(size_t)n * 512 + ol + r2];
      }
      if (ADD) {
        ushort4 old = *(const ushort4*)dp;
        vv[0] += b2f(old.x); vv[1] += b2f(old.y); vv[2] += b2f(old.z); vv[3] += b2f(old.w);
      }
      if (RELU) {
#pragma unroll
        for (int r2 = 0; r2 < 4; r2++) vv[r2] = fmaxf(vv[r2], 0.f);
      }
      ushort4 st = { f2b(vv[0]), f2b(vv[1]), f2b(vv[2]), f2b(vv[3]) };
      *(ushort4*)dp = st;
    }
  }
}

// ---- att[qn][pp][kn] = (1/sqrt(512)) * sum_c q[qn][pp][c]*k[kn][pp][c] ----
__global__ __launch_bounds__(256) void att2_kernel(
    const unsigned short* __restrict__ q, const unsigned short* __restrict__ k,
    float* __restrict__ att) {
  int kn = blockIdx.x, qn = blockIdx.y;
  int t = threadIdx.x, wv = t >> 6, l = t & 63;
  const unsigned short* qb = q + (size_t)qn * ACT_N;
  const unsigned short* kb = k + (size_t)kn * ACT_N;
  for (int i = wv; i < 196; i += 4) {
    int pp = (i / 14 + 1) * 16 + (i % 14) + 1;
    bhalf8 qv = *(const bhalf8*)(qb + pp * 512 + l * 8);
    bhalf8 kv = *(const bhalf8*)(kb + pp * 512 + l * 8);
    float s = 0.f;
#pragma unroll
    for (int j = 0; j < 8; j++)
      s += b2f((unsigned short)qv[j]) * b2f((unsigned short)kv[j]);
#pragma unroll
    for (int off = 32; off >= 1; off >>= 1) s += __shfl_xor(s, off);
    if (l == 0) att[((size_t)qn * 256 + pp) * 32 + kn] = s * 0.044194173824159216f;
  }
}

// ---- softmax over kn (32 contiguous f32 per (qn,pp)) ----
__global__ void softmax2_kernel(float* __restrict__ att) {
  int qn = blockIdx.x, t = threadIdx.x;
  if (t >= 196) return;
  int pp = (t / 14 + 1) * 16 + (t % 14) + 1;
  float* a = att + ((size_t)qn * 256 + pp) * 32;
  float v[32]; float m = -3.4e38f;
#pragma unroll
  for (int i = 0; i < 32; i++) { v[i] = a[i]; m = fmaxf(m, v[i]); }
  float s = 0.f;
#pragma unroll
  for (int i = 0; i < 32; i++) { v[i] = __expf(v[i] - m); s += v[i]; }
  float inv = 1.f / s;
#pragma unroll
  for (int i = 0; i < 32; i++) a[i] = v[i] * inv;
}

// ---- vf[qn][p][c] = sum_kn att[qn][p][kn]*v[kn][p][c]; border rows -> 0 ----
__global__ __launch_bounds__(256) void vf2_kernel(
    const float* __restrict__ att, const unsigned short* __restrict__ v,
    unsigned short* __restrict__ o) {
  int p = blockIdx.x, t = threadIdx.x;
  int h = p >> 4, w = p & 15;
  if (h < 1 || h > 14 || w < 1 || w > 14) {
    for (int qn = 0; qn < 32; qn++)
      *(unsigned int*)(o + ((size_t)qn * 256 + p) * 512 + t * 2) = 0u;
    return;
  }
  __shared__ float attS[1024];
  __shared__ unsigned short vS[32 * 512];
#pragma unroll
  for (int i = 0; i < 4; i++) {
    int idx = t + i * 256;
    int qn = idx >> 5, kn = idx & 31;
    attS[idx] = att[((size_t)qn * 256 + p) * 32 + kn];
  }
#pragma unroll
  for (int i = 0; i < 8; i++) {
    int u = t + i * 256;
    int kn = u >> 6, cu = (u & 63) * 8;
    *(bhalf8*)&vS[kn * 512 + cu] = *(const bhalf8*)(v + ((size_t)kn * 256 + p) * 512 + cu);
  }
  __syncthreads();
  int c2 = t * 2;
  for (int qn = 0; qn < 32; qn++) {
    float s0 = 0.f, s1 = 0.f;
#pragma unroll
    for (int kn = 0; kn < 32; kn++) {
      float a = attS[qn * 32 + kn];
      unsigned int vv = *(const unsigned int*)&vS[kn * 512 + c2];
      s0 += a * b2f((unsigned short)vv);
      s1 += a * b2f((unsigned short)(vv >> 16));
    }
    unsigned int pkd = (unsigned int)f2b(s0) | ((unsigned int)f2b(s1) << 16);
    *(unsigned int*)(o + ((size_t)qn * 256 + p) * 512 + c2) = pkd;
  }
}

// ---- GroupNorm stats over interior (196 x 512) per n ----
__global__ __launch_bounds__(256) void gnstats2_kernel(
    const unsigned short* __restrict__ x, float* __restrict__ stats) {
  int n = blockIdx.x, t = threadIdx.x;
  const unsigned short* xb = x + (size_t)n * ACT_N;
  float s = 0.f, ss = 0.f;
  for (int i = 0; i < 196; i++) {
    int pp = (i / 14 + 1) * 16 + (i % 14) + 1;
    unsigned int vv = *(const unsigned int*)(xb + pp * 512 + t * 2);
    float a = b2f((unsigned short)vv), b = b2f((unsigned short)(vv >> 16));
    s += a + b; ss += a * a + b * b;
  }
#pragma unroll
  for (int off = 32; off >= 1; off >>= 1) { s += __shfl_xor(s, off); ss += __shfl_xor(ss, off); }
  __shared__ float sm[8];
  int wv = t >> 6, ln = t & 63;
  if (ln == 0) { sm[wv] = s; sm[4 + wv] = ss; }
  __syncthreads();
  if (t == 0) {
    stats[n * 2]     = sm[0] + sm[1] + sm[2] + sm[3];
    stats[n * 2 + 1] = sm[4] + sm[5] + sm[6] + sm[7];
  }
}

// ---- GroupNorm apply + affine + relu (interior only) ----
__global__ __launch_bounds__(256) void gnapply2_kernel(
    unsigned short* __restrict__ x, const float* __restrict__ stats,
    const float* __restrict__ gamma, const float* __restrict__ beta) {
  int n = blockIdx.y, t = threadIdx.x;
  int c2 = t * 2;
  unsigned short* xb = x + (size_t)n * ACT_N;
  const float M = 512.f * 196.f;
  float mu = stats[n * 2] / M;
  float var = stats[n * 2 + 1] / M - mu * mu;
  float inv = rsqrtf(var + 1e-5f);
  float g0 = gamma[c2], g1 = gamma[c2 + 1];
  float be0 = beta[c2], be1 = beta[c2 + 1];
  for (int j = 0; j < 28; j++) {
    int i = blockIdx.x * 28 + j;
    int pp = (i / 14 + 1) * 16 + (i % 14) + 1;
    unsigned int vv = *(unsigned int*)(xb + pp * 512 + c2);
    float a = (b2f((unsigned short)vv) - mu) * inv * g0 + be0;
    float b = (b2f((unsigned short)(vv >> 16)) - mu) * inv * g1 + be1;
    a = fmaxf(a, 0.f); b = fmaxf(b, 0.f);
    *(unsigned int*)(xb + pp * 512 + c2) =
        (unsigned int)f2b(a) | ((unsigned int)f2b(b) << 16);
  }
}

// ---- final: mean over interior 196 -> out[n][1024+c] (f32) ----
__global__ void fmean2_kernel(const unsigned short* __restrict__ x, float* __restrict__ out) {
  int n = blockIdx.x, t = threadIdx.x;
  const unsigned short* xb = x + (size_t)n * ACT_N;
  float s0 = 0.f, s1 = 0.f;
  for (int i = 0; i < 196; i++) {
    int pp = (i / 14 + 1) * 16 + (i % 14) + 1;
    unsigned int vv = *(const unsigned int*)(xb + pp * 512 + t * 2);
    s0 += b2f((unsigned short)vv);
    s1 += b2f((unsigned short)(vv >> 16));
  }
  out[(size_t)n * 1536 + 1024 + t * 2]     = s0 * (1.f / 196.f);
  out[(size_t)n * 1536 + 1024 + t * 2 + 1] = s1 * (1.f / 196.f);
}

extern "C" void kernel_launch(void* const* d_in, const int* in_sizes, int n_in,
                              void* d_out, int out_size, void* d_ws, size_t ws_size,
                              hipStream_t stream) {
  const float* x     = (const float*)d_in[0];
  const float* feat  = (const float*)d_in[1];
  const int*   rois  = (const int*)d_in[2];
  const float* w1    = (const float*)d_in[3];
  const float* w2    = (const float*)d_in[4];
  const float* wq    = (const float*)d_in[5];
  const float* wk    = (const float*)d_in[6];
  const float* wv    = (const float*)d_in[7];
  const float* wm    = (const float*)d_in[8];
  const float* gamma = (const float*)d_in[9];
  const float* beta  = (const float*)d_in[10];
  float* out = (float*)d_out;

  // ---- workspace layout ----
  float* wsf   = (float*)d_ws;
  float* xp    = wsf;                // 32768
  float* bias1 = xp + 32768;         // 16384
  float* stats = bias1 + 16384;      // 64
  float* att   = stats + 64;         // 262144  ([qn][pp][kn] f32)
  unsigned short* ub    = (unsigned short*)(att + 262144);
  unsigned short* featT = ub;                    // 8*256*1024   = 2097152
  unsigned short* W1g   = featT + 2097152;       // 512*1024     = 524288
  unsigned short* Wg2   = W1g + 524288;          // 13*W3SZ      = 30670848
  unsigned short* bufq  = Wg2 + 30670848;        // 4194304 each, q/k/v contiguous
  unsigned short* bufk  = bufq + 4194304;
  unsigned short* bufv  = bufk + 4194304;
  unsigned short* bufx  = bufv + 4194304;

  // bufx border rows must be zero (only interior ever written by convs)
  hipMemsetAsync(bufx, 0, (size_t)4194304 * 2, stream);

  pool_max_kernel<<<8192, 256, 0, stream>>>(x, xp, out);
  bias1_kernel<<<4096, 256, 0, stream>>>(w1, xp, bias1);
  wprep3_kernel<<<dim3(16, 8, 13), 256, 0, stream>>>(w2, wq, wk, wv, wm, Wg2);
  w1prep_kernel<<<dim3(32, 8), 256, 0, stream>>>(w1, W1g);
  ftprep_kernel<<<dim3(4, 16, 8), 256, 0, stream>>>(feat, featT);

  // conv1: 1x1, K=1024, +bias1, relu, full 16x16 output -> bufq
  conv_mfma_kernel<1, 1024, 4, 4, 1, true, false, true, false>
      <<<dim3(8, 32), 256, 0, stream>>>(featT, rois, W1g, bias1, bufq);
  // conv2: valid 3x3 -> padded interior of bufx, relu
  conv_mfma_kernel<9, 512, 2, 4, 2, true, false, false, true>
      <<<dim3(16, 32), 128, 0, stream>>>(bufq, nullptr, Wg2, nullptr, bufx);

  for (int d = 0; d < 3; d++) {
    // q,k,v batched: O=1536 over contiguous blocked tensors / output buffers
    conv_mfma_kernel<9, 512, 2, 8, 1, false, false, false, true>
        <<<dim3(24, 32), 128, 0, stream>>>(bufx, nullptr,
            Wg2 + (size_t)(1 + 4 * d) * W3SZ, nullptr, bufq);
    att2_kernel<<<dim3(32, 32), 256, 0, stream>>>(bufq, bufk, att);
    softmax2_kernel<<<32, 256, 0, stream>>>(att);
    vf2_kernel<<<256, 256, 0, stream>>>(att, bufv, bufq);
    gnstats2_kernel<<<32, 256, 0, stream>>>(bufq, stats);
    gnapply2_kernel<<<dim3(7, 32), 256, 0, stream>>>(bufq, stats,
        gamma + d * 512, beta + d * 512);
    // wm conv + residual add into bufx
    conv_mfma_kernel<9, 512, 2, 4, 2, false, true, false, true>
        <<<dim3(16, 32), 128, 0, stream>>>(bufq, nullptr,
            Wg2 + (size_t)(4 + 4 * d) * W3SZ, nullptr, bufx);
  }

  fmean2_kernel<<<32, 256, 0, stream>>>(bufx, out);
}

// Round 5
// 924.498 us; speedup vs baseline: 7.6695x; 1.1498x over previous
//
#include <hip/hip_runtime.h>

// ---------------------------------------------------------------------------
// ACARHead forward, bf16-MFMA convs, 2-phase pipelined K-loop (double-buffered
// LDS, counted-vmcnt single barrier per K-step).
// Activation layout: bf16 [n][p=256][c] (c contiguous); 14x14 payload at
// rows/cols 1..14 of the 16x16 p-grid, border zero.
// ---------------------------------------------------------------------------

typedef __attribute__((ext_vector_type(8))) short bhalf8;
typedef __attribute__((ext_vector_type(4))) float floatx4;

#define ACT_N 131072   // 256*512 bf16 elements per sample
#define W3SZ  2359296  // 512*512*9 (also = blocked per-tensor short count)

__device__ inline float b2f(unsigned short u) {
  union { unsigned int i; float f; } x; x.i = ((unsigned int)u) << 16; return x.f;
}
__device__ inline unsigned short f2b(float f) {
  union { float f; unsigned int i; } x; x.f = f;
  return (unsigned short)((x.i + 0x7FFFu + ((x.i >> 16) & 1u)) >> 16);
}
__device__ inline void gload_lds16(const unsigned short* g, bhalf8* l) {
  __builtin_amdgcn_global_load_lds(
      (const __attribute__((address_space(1))) unsigned int*)(const void*)g,
      (__attribute__((address_space(3))) unsigned int*)(void*)l, 16, 0, 0);
}

// ---- AdaptiveMaxPool3d(1): max over 196, write xp (f32) and out[:,0:1024] ----
__global__ void pool_max_kernel(const float* __restrict__ x, float* __restrict__ xp,
                                float* __restrict__ out) {
  int tid = threadIdx.x;
  int wid = blockIdx.x * 4 + (tid >> 6);   // n*1024 + c
  int lane = tid & 63;
  int n = wid >> 10, c = wid & 1023;
  const float* p = x + (size_t)wid * 196;
  float v = -3.4e38f;
  v = fmaxf(v, p[lane]);
  v = fmaxf(v, p[lane + 64]);
  v = fmaxf(v, p[lane + 128]);
  if (lane < 4) v = fmaxf(v, p[lane + 192]);
#pragma unroll
  for (int off = 32; off >= 1; off >>= 1) v = fmaxf(v, __shfl_xor(v, off));
  if (lane == 0) { xp[wid] = v; out[(size_t)n * 1536 + c] = v; }
}

// ---- bias1[n][o] = sum_{c<1024} w1[o][1024+c] * xp[n][c]  (f32) ----
__global__ void bias1_kernel(const float* __restrict__ w1, const float* __restrict__ xp,
                             float* __restrict__ bias1) {
  int tid = threadIdx.x;
  int wid = blockIdx.x * 4 + (tid >> 6);   // n*512 + o
  int lane = tid & 63;
  int n = wid >> 9, o = wid & 511;
  const float* wr = w1 + (size_t)o * 2048 + 1024;
  const float* xr = xp + (size_t)n * 1024;
  float s = 0.f;
#pragma unroll
  for (int r = 0; r < 16; r++) { int c = lane + r * 64; s += wr[c] * xr[c]; }
#pragma unroll
  for (int off = 32; off >= 1; off >>= 1) s += __shfl_xor(s, off);
  if (lane == 0) bias1[wid] = s;
}

// ---- 3x3 weight prep -> blocked LDS-slot-linear layout ----
// Wg2[tensor][ot(8)][ks(16)][slot u(2304)][8 bf16], slot u: r=u>>6, o=u&63,
// t9=r>>2, kg=r&3; data = w[o0+o][c0+kg*8+j][t9].
__global__ __launch_bounds__(256) void wprep3_kernel(
    const float* __restrict__ w2, const float* __restrict__ wq,
    const float* __restrict__ wk, const float* __restrict__ wv,
    const float* __restrict__ wm, unsigned short* __restrict__ Wg2) {
  int ks = blockIdx.x, ot = blockIdx.y, tid = blockIdx.z;
  int t = threadIdx.x;
  const float* src;
  if (tid == 0) src = w2;
  else {
    int d = (tid - 1) >> 2, r = (tid - 1) & 3;
    src = (r == 0 ? wq : r == 1 ? wk : r == 2 ? wv : wm) + (size_t)d * W3SZ;
  }
  __shared__ unsigned short S[64 * 288];
  const float* sb = src + (size_t)ot * 64 * 4608 + (size_t)ks * 288;
  for (int j = 0; j < 72; j++) {
    int flat = j * 256 + t;          // < 18432
    int o = flat / 288, ci = flat % 288;
    S[flat] = f2b(sb[(size_t)o * 4608 + ci]);
  }
  __syncthreads();
  unsigned short* dst = Wg2 + (((size_t)(tid * 8 + ot) * 16 + ks) * 2304) * 8;
#pragma unroll
  for (int s = 0; s < 9; s++) {
    int u = t + s * 256;
    int r = u >> 6, o = u & 63;
    int t9 = r >> 2, kg = r & 3;
    bhalf8 v;
#pragma unroll
    for (int j = 0; j < 8; j++) v[j] = (short)S[o * 288 + (kg * 8 + j) * 9 + t9];
    *(bhalf8*)(dst + (size_t)u * 8) = v;
  }
}

// ---- conv1 weight prep -> blocked: W1g[ot(8)][ks(32)][slot(256)][8] ----
__global__ void w1prep_kernel(const float* __restrict__ w1, unsigned short* __restrict__ W1g) {
  int ks = blockIdx.x, ot = blockIdx.y, t = threadIdx.x;
  int kg = t >> 6, o = t & 63;
  const float* s = w1 + (size_t)(ot * 64 + o) * 2048 + ks * 32 + kg * 8;
  bhalf8 v;
#pragma unroll
  for (int j = 0; j < 8; j++) v[j] = (short)f2b(s[j]);
  *(bhalf8*)(W1g + (((size_t)ot * 32 + ks) * 256 + t) * 8) = v;
}

// ---- feat transpose: feat[img][c][p] f32 -> featT[img][p][c] bf16 ----
__global__ __launch_bounds__(256) void ftprep_kernel(
    const float* __restrict__ feat, unsigned short* __restrict__ featT) {
  int img = blockIdx.z, c0 = blockIdx.y * 64, p0 = blockIdx.x * 64;
  int t = threadIdx.x;
  int a = t >> 6, b = t & 63;
  __shared__ float S[64][65];
#pragma unroll
  for (int j = 0; j < 16; j++) {
    int r = a * 16 + j;
    S[r][b] = feat[((size_t)img * 1024 + c0 + r) * 256 + p0 + b];
  }
  __syncthreads();
#pragma unroll
  for (int j = 0; j < 16; j++) {
    int pl = a * 16 + j;
    featT[((size_t)img * 256 + p0 + pl) * 1024 + c0 + b] = f2b(S[b][pl]);
  }
}

// ---------------------------------------------------------------------------
// Unified MFMA conv, 2-phase pipelined (T3-min): STAGE(next) -> compute(cur)
// -> vmcnt(0) -> s_barrier. Double-buffered LDS via extern __shared__.
// 4 waves (256 thr), block tile 64o x 256p, per-wave 64o x 64p (NREP=4).
// LDS slots (16B): Xs[b][kg*256+p], Ws[b][(t9*4+kg)*64+o].
// ---------------------------------------------------------------------------
template <int TAPS, int KTOT, int WAVES, int NREP, int PSPLIT,
          bool RELU, bool ADD, bool BIAS, bool VALID>
__global__ __launch_bounds__(WAVES * 64) void conv_mfma_kernel(
    const unsigned short* __restrict__ Xg, const int* __restrict__ rois,
    const unsigned short* __restrict__ Wg, const float* __restrict__ bias,
    unsigned short* __restrict__ Out) {
  constexpr int THREADS = WAVES * 64;
  constexpr int WSLOTS = TAPS * 4 * 64;
  constexpr int NK = KTOT / 32;
  static_assert(PSPLIT * WAVES * NREP * 16 == 256, "p coverage");
  static_assert(1024 % THREADS == 0 && WSLOTS % THREADS == 0, "stage div");
  extern __shared__ __align__(16) char smem_raw[];
  bhalf8* lds = (bhalf8*)smem_raw;   // [Xs0|Xs1 (2*1024)] [Ws0|Ws1 (2*WSLOTS)]

  int n = blockIdx.y;
  int ot = blockIdx.x / PSPLIT;
  int pq = blockIdx.x % PSPLIT;
  int t = threadIdx.x;
  int wv = t >> 6, l = t & 63, l15 = l & 15, l4 = l >> 4;
  int pbase = (pq * WAVES + wv) * (NREP * 16);
  const unsigned short* xb =
      Xg + (rois ? (size_t)rois[n * 5] * 256 * KTOT : (size_t)n * 256 * KTOT);
  floatx4 acc[4][NREP] = {};

  auto STAGE = [&](int b, int ks) {
    bhalf8* Xs = lds + b * 1024;
    bhalf8* Ws = lds + 2048 + b * WSLOTS;
    const int c0 = ks * 32;
#pragma unroll
    for (int i = 0; i < 1024 / THREADS; i++) {
      int base = i * THREADS + wv * 64;
      int u = base + l;
      int p = u & 255, kg = u >> 8;
      gload_lds16(xb + (size_t)p * KTOT + c0 + kg * 8, Xs + base);
    }
    const unsigned short* wb = Wg + ((size_t)ot * NK + ks) * (WSLOTS * 8);
#pragma unroll
    for (int i = 0; i < WSLOTS / THREADS; i++) {
      int base = i * THREADS + wv * 64;
      gload_lds16(wb + (size_t)(base + l) * 8, Ws + base);
    }
  };

  STAGE(0, 0);
  asm volatile("s_waitcnt vmcnt(0)" ::: "memory");
  __builtin_amdgcn_s_barrier();

  int cur = 0;
  for (int ks = 0; ks < NK; ks++) {
    if (ks + 1 < NK) STAGE(cur ^ 1, ks + 1);
    __builtin_amdgcn_sched_barrier(0);
    const bhalf8* Xs = lds + cur * 1024;
    const bhalf8* Ws = lds + 2048 + cur * WSLOTS;

    if constexpr (TAPS == 9) {
#pragma unroll
      for (int dw = 0; dw < 3; dw++) {
        bhalf8 BW[NREP + 2];
#pragma unroll
        for (int w10 = 0; w10 < NREP + 2; w10++) {
          int row = (pbase + w10 * 16 + l15 + dw) & 255;
          BW[w10] = Xs[l4 * 256 + row];
        }
#pragma unroll
        for (int dh = 0; dh < 3; dh++) {
          const int rr = (dh * 3 + dw) * 4 + l4;
          bhalf8 A[4];
#pragma unroll
          for (int of = 0; of < 4; of++) A[of] = Ws[rr * 64 + of * 16 + l15];
#pragma unroll
          for (int of = 0; of < 4; of++)
#pragma unroll
            for (int pf = 0; pf < NREP; pf++)
              acc[of][pf] = __builtin_amdgcn_mfma_f32_16x16x32_bf16(
                  A[of], BW[pf + dh], acc[of][pf], 0, 0, 0);
        }
      }
    } else {
      bhalf8 B[NREP];
#pragma unroll
      for (int pf = 0; pf < NREP; pf++) {
        int row = (pbase + pf * 16 + l15) & 255;
        B[pf] = Xs[l4 * 256 + row];
      }
#pragma unroll
      for (int of = 0; of < 4; of++) {
        bhalf8 A = Ws[l4 * 64 + of * 16 + l15];
#pragma unroll
        for (int pf = 0; pf < NREP; pf++)
          acc[of][pf] = __builtin_amdgcn_mfma_f32_16x16x32_bf16(
              A, B[pf], acc[of][pf], 0, 0, 0);
      }
    }
    asm volatile("s_waitcnt vmcnt(0)" ::: "memory");
    __builtin_amdgcn_s_barrier();
    cur ^= 1;
  }

#pragma unroll
  for (int of = 0; of < 4; of++) {
    int og = ot * 64 + of * 16 + l4 * 4;
    int tensor = og >> 9, ol = og & 511;
#pragma unroll
    for (int pf = 0; pf < NREP; pf++) {
      int p = pbase + pf * 16 + l15;
      int po = p;
      if (VALID) {
        int h = p >> 4, w = p & 15;
        if (h >= 14 || w >= 14) continue;
        po = (h + 1) * 16 + (w + 1);
      }
      unsigned short* dp = Out + (((size_t)tensor * 32 + n) * 256 + po) * 512 + ol;
      float vv[4];
#pragma unroll
      for (int r2 = 0; r2 < 4; r2++) vv[r2] = acc[of][pf][r2];
      if (BIAS) {
#pragma unroll
        for (int r2 = 0; r2 < 4; r2++) vv[r2] += bias[(size_t)n * 512 + ol + r2];
      }
      if (ADD) {
        ushort4 old = *(const ushort4*)dp;
        vv[0] += b2f(old.x); vv[1] += b2f(old.y); vv[2] += b2f(old.z); vv[3] += b2f(old.w);
      }
      if (RELU) {
#pragma unroll
        for (int r2 = 0; r2 < 4; r2++) vv[r2] = fmaxf(vv[r2], 0.f);
      }
      ushort4 st = { f2b(vv[0]), f2b(vv[1]), f2b(vv[2]), f2b(vv[3]) };
      *(ushort4*)dp = st;
    }
  }
}

// ---- att[qn][pp][kn] = (1/sqrt(512)) * sum_c q[qn][pp][c]*k[kn][pp][c] ----
__global__ __launch_bounds__(256) void att2_kernel(
    const unsigned short* __restrict__ q, const unsigned short* __restrict__ k,
    float* __restrict__ att) {
  int kn = blockIdx.x, qn = blockIdx.y;
  int t = threadIdx.x, wv = t >> 6, l = t & 63;
  const unsigned short* qb = q + (size_t)qn * ACT_N;
  const unsigned short* kb = k + (size_t)kn * ACT_N;
  for (int i = wv; i < 196; i += 4) {
    int pp = (i / 14 + 1) * 16 + (i % 14) + 1;
    bhalf8 qv = *(const bhalf8*)(qb + pp * 512 + l * 8);
    bhalf8 kv = *(const bhalf8*)(kb + pp * 512 + l * 8);
    float s = 0.f;
#pragma unroll
    for (int j = 0; j < 8; j++)
      s += b2f((unsigned short)qv[j]) * b2f((unsigned short)kv[j]);
#pragma unroll
    for (int off = 32; off >= 1; off >>= 1) s += __shfl_xor(s, off);
    if (l == 0) att[((size_t)qn * 256 + pp) * 32 + kn] = s * 0.044194173824159216f;
  }
}

// ---- softmax over kn (32 contiguous f32 per (qn,pp)) ----
__global__ void softmax2_kernel(float* __restrict__ att) {
  int qn = blockIdx.x, t = threadIdx.x;
  if (t >= 196) return;
  int pp = (t / 14 + 1) * 16 + (t % 14) + 1;
  float* a = att + ((size_t)qn * 256 + pp) * 32;
  float v[32]; float m = -3.4e38f;
#pragma unroll
  for (int i = 0; i < 32; i++) { v[i] = a[i]; m = fmaxf(m, v[i]); }
  float s = 0.f;
#pragma unroll
  for (int i = 0; i < 32; i++) { v[i] = __expf(v[i] - m); s += v[i]; }
  float inv = 1.f / s;
#pragma unroll
  for (int i = 0; i < 32; i++) a[i] = v[i] * inv;
}

// ---- vf[qn][p][c] = sum_kn att[qn][p][kn]*v[kn][p][c]; border rows -> 0 ----
__global__ __launch_bounds__(256) void vf2_kernel(
    const float* __restrict__ att, const unsigned short* __restrict__ v,
    unsigned short* __restrict__ o) {
  int p = blockIdx.x, t = threadIdx.x;
  int h = p >> 4, w = p & 15;
  if (h < 1 || h > 14 || w < 1 || w > 14) {
    for (int qn = 0; qn < 32; qn++)
      *(unsigned int*)(o + ((size_t)qn * 256 + p) * 512 + t * 2) = 0u;
    return;
  }
  __shared__ float attS[1024];
  __shared__ unsigned short vS[32 * 512];
#pragma unroll
  for (int i = 0; i < 4; i++) {
    int idx = t + i * 256;
    int qn = idx >> 5, kn = idx & 31;
    attS[idx] = att[((size_t)qn * 256 + p) * 32 + kn];
  }
#pragma unroll
  for (int i = 0; i < 8; i++) {
    int u = t + i * 256;
    int kn = u >> 6, cu = (u & 63) * 8;
    *(bhalf8*)&vS[kn * 512 + cu] = *(const bhalf8*)(v + ((size_t)kn * 256 + p) * 512 + cu);
  }
  __syncthreads();
  int c2 = t * 2;
  for (int qn = 0; qn < 32; qn++) {
    float s0 = 0.f, s1 = 0.f;
#pragma unroll
    for (int kn = 0; kn < 32; kn++) {
      float a = attS[qn * 32 + kn];
      unsigned int vv = *(const unsigned int*)&vS[kn * 512 + c2];
      s0 += a * b2f((unsigned short)vv);
      s1 += a * b2f((unsigned short)(vv >> 16));
    }
    unsigned int pkd = (unsigned int)f2b(s0) | ((unsigned int)f2b(s1) << 16);
    *(unsigned int*)(o + ((size_t)qn * 256 + p) * 512 + c2) = pkd;
  }
}

// ---- GroupNorm stats over interior (196 x 512) per n ----
__global__ __launch_bounds__(256) void gnstats2_kernel(
    const unsigned short* __restrict__ x, float* __restrict__ stats) {
  int n = blockIdx.x, t = threadIdx.x;
  const unsigned short* xb = x + (size_t)n * ACT_N;
  float s = 0.f, ss = 0.f;
  for (int i = 0; i < 196; i++) {
    int pp = (i / 14 + 1) * 16 + (i % 14) + 1;
    unsigned int vv = *(const unsigned int*)(xb + pp * 512 + t * 2);
    float a = b2f((unsigned short)vv), b = b2f((unsigned short)(vv >> 16));
    s += a + b; ss += a * a + b * b;
  }
#pragma unroll
  for (int off = 32; off >= 1; off >>= 1) { s += __shfl_xor(s, off); ss += __shfl_xor(ss, off); }
  __shared__ float sm[8];
  int wv = t >> 6, ln = t & 63;
  if (ln == 0) { sm[wv] = s; sm[4 + wv] = ss; }
  __syncthreads();
  if (t == 0) {
    stats[n * 2]     = sm[0] + sm[1] + sm[2] + sm[3];
    stats[n * 2 + 1] = sm[4] + sm[5] + sm[6] + sm[7];
  }
}

// ---- GroupNorm apply + affine + relu (interior only) ----
__global__ __launch_bounds__(256) void gnapply2_kernel(
    unsigned short* __restrict__ x, const float* __restrict__ stats,
    const float* __restrict__ gamma, const float* __restrict__ beta) {
  int n = blockIdx.y, t = threadIdx.x;
  int c2 = t * 2;
  unsigned short* xb = x + (size_t)n * ACT_N;
  const float M = 512.f * 196.f;
  float mu = stats[n * 2] / M;
  float var = stats[n * 2 + 1] / M - mu * mu;
  float inv = rsqrtf(var + 1e-5f);
  float g0 = gamma[c2], g1 = gamma[c2 + 1];
  float be0 = beta[c2], be1 = beta[c2 + 1];
  for (int j = 0; j < 28; j++) {
    int i = blockIdx.x * 28 + j;
    int pp = (i / 14 + 1) * 16 + (i % 14) + 1;
    unsigned int vv = *(unsigned int*)(xb + pp * 512 + c2);
    float a = (b2f((unsigned short)vv) - mu) * inv * g0 + be0;
    float b = (b2f((unsigned short)(vv >> 16)) - mu) * inv * g1 + be1;
    a = fmaxf(a, 0.f); b = fmaxf(b, 0.f);
    *(unsigned int*)(xb + pp * 512 + c2) =
        (unsigned int)f2b(a) | ((unsigned int)f2b(b) << 16);
  }
}

// ---- final: mean over interior 196 -> out[n][1024+c] (f32) ----
__global__ void fmean2_kernel(const unsigned short* __restrict__ x, float* __restrict__ out) {
  int n = blockIdx.x, t = threadIdx.x;
  const unsigned short* xb = x + (size_t)n * ACT_N;
  float s0 = 0.f, s1 = 0.f;
  for (int i = 0; i < 196; i++) {
    int pp = (i / 14 + 1) * 16 + (i % 14) + 1;
    unsigned int vv = *(const unsigned int*)(xb + pp * 512 + t * 2);
    s0 += b2f((unsigned short)vv);
    s1 += b2f((unsigned short)(vv >> 16));
  }
  out[(size_t)n * 1536 + 1024 + t * 2]     = s0 * (1.f / 196.f);
  out[(size_t)n * 1536 + 1024 + t * 2 + 1] = s1 * (1.f / 196.f);
}

extern "C" void kernel_launch(void* const* d_in, const int* in_sizes, int n_in,
                              void* d_out, int out_size, void* d_ws, size_t ws_size,
                              hipStream_t stream) {
  const float* x     = (const float*)d_in[0];
  const float* feat  = (const float*)d_in[1];
  const int*   rois  = (const int*)d_in[2];
  const float* w1    = (const float*)d_in[3];
  const float* w2    = (const float*)d_in[4];
  const float* wq    = (const float*)d_in[5];
  const float* wk    = (const float*)d_in[6];
  const float* wv    = (const float*)d_in[7];
  const float* wm    = (const float*)d_in[8];
  const float* gamma = (const float*)d_in[9];
  const float* beta  = (const float*)d_in[10];
  float* out = (float*)d_out;

  // ---- workspace layout ----
  float* wsf   = (float*)d_ws;
  float* xp    = wsf;                // 32768
  float* bias1 = xp + 32768;         // 16384
  float* stats = bias1 + 16384;      // 64
  float* att   = stats + 64;         // 262144  ([qn][pp][kn] f32)
  unsigned short* ub    = (unsigned short*)(att + 262144);
  unsigned short* featT = ub;                    // 8*256*1024   = 2097152
  unsigned short* W1g   = featT + 2097152;       // 512*1024     = 524288
  unsigned short* Wg2   = W1g + 524288;          // 13*W3SZ      = 30670848
  unsigned short* bufq  = Wg2 + 30670848;        // 4194304 each, q/k/v contiguous
  unsigned short* bufk  = bufq + 4194304;
  unsigned short* bufv  = bufk + 4194304;
  unsigned short* bufx  = bufv + 4194304;

  // allow >64KB dynamic LDS for the pipelined conv instantiations
  hipFuncSetAttribute(
      reinterpret_cast<const void*>(&conv_mfma_kernel<9, 512, 4, 4, 1, true, false, false, true>),
      hipFuncAttributeMaxDynamicSharedMemorySize, 106496);
  hipFuncSetAttribute(
      reinterpret_cast<const void*>(&conv_mfma_kernel<9, 512, 4, 4, 1, false, false, false, true>),
      hipFuncAttributeMaxDynamicSharedMemorySize, 106496);
  hipFuncSetAttribute(
      reinterpret_cast<const void*>(&conv_mfma_kernel<9, 512, 4, 4, 1, false, true, false, true>),
      hipFuncAttributeMaxDynamicSharedMemorySize, 106496);

  // bufx border rows must be zero (only interior ever written by convs)
  hipMemsetAsync(bufx, 0, (size_t)4194304 * 2, stream);

  pool_max_kernel<<<8192, 256, 0, stream>>>(x, xp, out);
  bias1_kernel<<<4096, 256, 0, stream>>>(w1, xp, bias1);
  wprep3_kernel<<<dim3(16, 8, 13), 256, 0, stream>>>(w2, wq, wk, wv, wm, Wg2);
  w1prep_kernel<<<dim3(32, 8), 256, 0, stream>>>(w1, W1g);
  ftprep_kernel<<<dim3(4, 16, 8), 256, 0, stream>>>(feat, featT);

  // conv1: 1x1, K=1024, +bias1, relu, full 16x16 output -> bufq
  conv_mfma_kernel<1, 1024, 4, 4, 1, true, false, true, false>
      <<<dim3(8, 32), 256, 40960, stream>>>(featT, rois, W1g, bias1, bufq);
  // conv2: valid 3x3 -> padded interior of bufx, relu
  conv_mfma_kernel<9, 512, 4, 4, 1, true, false, false, true>
      <<<dim3(8, 32), 256, 106496, stream>>>(bufq, nullptr, Wg2, nullptr, bufx);

  for (int d = 0; d < 3; d++) {
    // q,k,v batched: O=1536 over contiguous blocked tensors / output buffers
    conv_mfma_kernel<9, 512, 4, 4, 1, false, false, false, true>
        <<<dim3(24, 32), 256, 106496, stream>>>(bufx, nullptr,
            Wg2 + (size_t)(1 + 4 * d) * W3SZ, nullptr, bufq);
    att2_kernel<<<dim3(32, 32), 256, 0, stream>>>(bufq, bufk, att);
    softmax2_kernel<<<32, 256, 0, stream>>>(att);
    vf2_kernel<<<256, 256, 0, stream>>>(att, bufv, bufq);
    gnstats2_kernel<<<32, 256, 0, stream>>>(bufq, stats);
    gnapply2_kernel<<<dim3(7, 32), 256, 0, stream>>>(bufq, stats,
        gamma + d * 512, beta + d * 512);
    // wm conv + residual add into bufx
    conv_mfma_kernel<9, 512, 4, 4, 1, false, true, false, true>
        <<<dim3(8, 32), 256, 106496, stream>>>(bufq, nullptr,
            Wg2 + (size_t)(4 + 4 * d) * W3SZ, nullptr, bufx);
  }

  fmean2_kernel<<<32, 256, 0, stream>>>(bufx, out);
}